// Round 6
// baseline (404.206 us; speedup 1.0000x reference)
//
#include <hip/hip_runtime.h>
#include <hip/hip_cooperative_groups.h>
#include <math.h>

namespace cg = cooperative_groups;

#define N_NODES 20000
#define N_EDGES 320000
#define EMB 128
#define HID 512          // 4*EMB
#define PQ_STRIDE 1024   // P (512, bias-folded) + Q (512) per node
#define ROWS_PER_BLOCK 8
#define SC_CAP 1024      // LDS score cache per block (spill path for skew)
#define CSR_BLOCKS 120   // cooperative grid: guaranteed co-resident (<=256 CUs)

typedef float v2f __attribute__((ext_vector_type(2)));

#if defined(__has_builtin)
#if __has_builtin(__builtin_elementwise_fma)
#define V2FMA(a, b, c) __builtin_elementwise_fma((a), (b), (c))
#else
#define V2FMA(a, b, c) ((a) * (b) + (c))
#endif
#else
#define V2FMA(a, b, c) ((a) * (b) + (c))
#endif

// ---------------------------------------------------------------------------
__device__ __forceinline__ int wave_incl_scan(int v, int lane) {
#pragma unroll
    for (int off = 1; off < 64; off <<= 1) {
        int t = __shfl_up(v, off, 64);
        if (lane >= off) v += t;
    }
    return v;
}

// ---------------------------------------------------------------------------
// ONE cooperative kernel replacing the 6-kernel CSR chain (init, histogram,
// 3-stage scan, scatter). Work is tiny (~0.7M simple ops); the old chain's
// cost was mostly launch/drain gaps. grid.sync() = device-scope barrier.
// ---------------------------------------------------------------------------
__global__ __launch_bounds__(1024) void build_csr(
    const int* __restrict__ row, const int* __restrict__ col,
    int* __restrict__ deg, int* __restrict__ totals,
    int* __restrict__ cursor, int* __restrict__ offs,
    int* __restrict__ perm, int* __restrict__ row_s, int* __restrict__ col_s)
{
    cg::grid_group grid = cg::this_grid();
    const int tid = threadIdx.x, bid = blockIdx.x;
    const int gtid = bid * 1024 + tid;
    const int gsz = CSR_BLOCKS * 1024;
    const int lane = tid & 63, w = tid >> 6;
    __shared__ int wsum[16];

    // phase 0: zero histogram
    for (int i = gtid; i < N_NODES; i += gsz) deg[i] = 0;
    if (gtid == 0) offs[N_NODES] = N_EDGES;
    grid.sync();

    // phase 1: degree histogram
    for (int e = gtid; e < N_EDGES; e += gsz) atomicAdd(&deg[row[e]], 1);
    grid.sync();

    // phase 2a: block-local exclusive scan over 1024-node chunks
    const int nchunks = (N_NODES + 1023) >> 10;   // 20
    int part = 0;
    if (bid < nchunks) {
        const int i = bid * 1024 + tid;
        int v = (i < N_NODES) ? deg[i] : 0;
        int incl = wave_incl_scan(v, lane);
        if (lane == 63) wsum[w] = incl;
        __syncthreads();
        if (w == 0) {
            int x = (lane < 16) ? wsum[lane] : 0;
            int xs = wave_incl_scan(x, lane);
            if (lane < 16) wsum[lane] = xs - x;   // exclusive wave offsets
            if (lane == 15) totals[bid] = xs;     // chunk total
        }
        __syncthreads();
        part = wsum[w] + incl - v;
    }
    grid.sync();

    // phase 2b: scan the 20 chunk totals -> carries (block 0, one wave)
    if (bid == 0 && tid < 64) {
        int v = (tid < nchunks) ? totals[tid] : 0;
        int incl = wave_incl_scan(v, tid);
        if (tid < nchunks) totals[tid] = incl - v;  // carry
    }
    grid.sync();

    // phase 2c: apply carries -> offs + cursor
    if (bid < nchunks) {
        const int i = bid * 1024 + tid;
        if (i < N_NODES) {
            int o = part + totals[bid];
            cursor[i] = o;
            offs[i] = o;
        }
    }
    grid.sync();

    // phase 3: scatter edges into row-sorted order
    for (int e = gtid; e < N_EDGES; e += gsz) {
        int r = row[e];
        int pos = atomicAdd(&cursor[r], 1);
        perm[pos] = e;
        row_s[pos] = r;
        col_s[pos] = col[e];
    }
}

// ---------------------------------------------------------------------------
// GEMM: PQ[:,0:512] = h@W1[0:128,:] + b1 ; PQ[:,512:1024] = h@W1[128:256,:]
// 128x128 tile, BK=16, 512 threads (8 waves), 4x8 micro-tile (v_pk_fma),
// LDS double-buffer -> one barrier per K-tile.
// ---------------------------------------------------------------------------
#define TM 128
#define TN 128
#define BK 16
#define NTILES (EMB / BK)   // 8

__global__ __launch_bounds__(512) void gemm_pq(
    const float* __restrict__ h, const float* __restrict__ W1,
    const float* __restrict__ b1, float* __restrict__ PQ)
{
    __shared__ float As[2][BK][TM + 4];   // transposed A, stride 132
    __shared__ float Bs[2][BK][TN];

    const int tid = threadIdx.x;
    const int nt  = blockIdx.x;           // 0..7
    const int mt  = blockIdx.y;           // 0..156
    const int m_base = mt * TM;

    const int a_m = tid >> 2;             // 0..127
    const int a_k = (tid & 3) << 2;       // 0,4,8,12
    const int  row_a = m_base + a_m;
    const bool a_ok  = row_a < N_NODES;
    const float* __restrict__ hrow = h + (size_t)row_a * EMB + a_k;

    const int b_k = tid >> 5;             // 0..15
    const int b_n = (tid & 31) << 2;      // 0..124
    const int w_row_off = (nt < 4) ? 0 : 128;
    const int w_col     = (nt & 3) * TN + b_n;
    const float* __restrict__ wrow = W1 + (size_t)(w_row_off + b_k) * HID + w_col;

    const int ty = tid >> 4, tx = tid & 15;
    const int cm = ty << 2, cn = tx << 2;

    v2f acc[4][4] = {};

    float4 pa, pb;
    pa = make_float4(0.f, 0.f, 0.f, 0.f);
    if (a_ok) pa = *(const float4*)(hrow);
    pb = *(const float4*)(wrow);
    As[0][a_k + 0][a_m] = pa.x;
    As[0][a_k + 1][a_m] = pa.y;
    As[0][a_k + 2][a_m] = pa.z;
    As[0][a_k + 3][a_m] = pa.w;
    *(float4*)&Bs[0][b_k][b_n] = pb;
    __syncthreads();

    for (int t = 0; t < NTILES; ++t) {
        const int cur = t & 1;
        if (t + 1 < NTILES) {
            const int k0 = (t + 1) * BK;
            pa = make_float4(0.f, 0.f, 0.f, 0.f);
            if (a_ok) pa = *(const float4*)(hrow + k0);
            pb = *(const float4*)(wrow + (size_t)k0 * HID);
        }

#pragma unroll
        for (int kk = 0; kk < BK; ++kk) {
            float4 a4 = *(const float4*)&As[cur][kk][cm];
            float4 b0 = *(const float4*)&Bs[cur][kk][cn];
            float4 b1v = *(const float4*)&Bs[cur][kk][cn + 64];
            v2f bp[4] = {(v2f){b0.x, b0.y}, (v2f){b0.z, b0.w},
                         (v2f){b1v.x, b1v.y}, (v2f){b1v.z, b1v.w}};
            float a[4] = {a4.x, a4.y, a4.z, a4.w};
#pragma unroll
            for (int i = 0; i < 4; ++i) {
                v2f ai = (v2f){a[i], a[i]};
#pragma unroll
                for (int j = 0; j < 4; ++j)
                    acc[i][j] = V2FMA(ai, bp[j], acc[i][j]);
            }
        }

        if (t + 1 < NTILES) {
            const int nxt = 1 - cur;
            As[nxt][a_k + 0][a_m] = pa.x;
            As[nxt][a_k + 1][a_m] = pa.y;
            As[nxt][a_k + 2][a_m] = pa.z;
            As[nxt][a_k + 3][a_m] = pa.w;
            *(float4*)&Bs[nxt][b_k][b_n] = pb;
            __syncthreads();
        }
    }

    const int col_base = nt * TN;
    v2f bias[4] = {{0.f,0.f},{0.f,0.f},{0.f,0.f},{0.f,0.f}};
    if (nt < 4) {  // bias fold: P half only
        float4 bv0 = *(const float4*)(b1 + col_base + cn);
        float4 bv1 = *(const float4*)(b1 + col_base + cn + 64);
        bias[0] = (v2f){bv0.x, bv0.y};
        bias[1] = (v2f){bv0.z, bv0.w};
        bias[2] = (v2f){bv1.x, bv1.y};
        bias[3] = (v2f){bv1.z, bv1.w};
    }

#pragma unroll
    for (int i = 0; i < 4; ++i) {
        const int r = m_base + cm + i;
        if (r < N_NODES) {
            float* dst = PQ + (size_t)r * PQ_STRIDE + col_base;
            v2f c0 = acc[i][0] + bias[0], c1 = acc[i][1] + bias[1];
            v2f c2 = acc[i][2] + bias[2], c3 = acc[i][3] + bias[3];
            *(float4*)(dst + cn)      = make_float4(c0.x, c0.y, c1.x, c1.y);
            *(float4*)(dst + cn + 64) = make_float4(c2.x, c2.y, c3.x, c3.y);
        }
    }
}

// ---------------------------------------------------------------------------
// Fused edge phase. Block owns 8 consecutive rows (complete segments);
// 2500 blocks -> ~2x the waves in flight vs RPB=16 (occupancy was the
// binding constraint: 47% with grid-limited 5000 waves).
// Phase 1: wave-per-edge MLP, unroll x2. Phase 2: wave-per-row softmax +
// relaxed bernoulli + outputs.
// ---------------------------------------------------------------------------
__global__ __launch_bounds__(256) void fused_edge(
    const float* __restrict__ PQ,
    const float* __restrict__ W2, const float* __restrict__ b2,
    const int* __restrict__ row_s, const int* __restrict__ col_s,
    const int* __restrict__ perm, const int* __restrict__ offs,
    const float* __restrict__ u, const int* __restrict__ edge_mask,
    const int* __restrict__ hierarchy,
    float* __restrict__ scores, float* __restrict__ out_y,
    float* __restrict__ out_mask, float* __restrict__ out_causal,
    float* __restrict__ out_spu)
{
    __shared__ float sc_lds[SC_CAP];

    const int r0 = blockIdx.x * ROWS_PER_BLOCK;
    const int r1 = (r0 + ROWS_PER_BLOCK < N_NODES) ? r0 + ROWS_PER_BLOCK : N_NODES;
    const int e0 = offs[r0];
    const int e1 = offs[r1];
    const int tid = threadIdx.x, lane = tid & 63, w = tid >> 6;
    const int j0 = lane << 2;

    const float4 w0 = *(const float4*)(W2 + j0);
    const float4 w1 = *(const float4*)(W2 + 256 + j0);
    const float bias2 = b2[0];

    // ---- phase 1: scores, two edges per wave-iteration ----
    for (int i0 = e0 + (w << 1); i0 < e1; i0 += 8) {
        const int  iA   = i0;
        const bool hasB = (i0 + 1) < e1;
        const int  iB   = hasB ? i0 + 1 : i0;

        const int rA = row_s[iA], cA = col_s[iA];
        const int rB = row_s[iB], cB = col_s[iB];
        const float* __restrict__ pA = PQ + (size_t)rA * PQ_STRIDE;
        const float* __restrict__ qA = PQ + (size_t)cA * PQ_STRIDE + HID;
        const float* __restrict__ pB = PQ + (size_t)rB * PQ_STRIDE;
        const float* __restrict__ qB = PQ + (size_t)cB * PQ_STRIDE + HID;

        float4 pA0 = *(const float4*)(pA + j0);
        float4 pA1 = *(const float4*)(pA + 256 + j0);
        float4 qA0 = *(const float4*)(qA + j0);
        float4 qA1 = *(const float4*)(qA + 256 + j0);
        float4 pB0 = *(const float4*)(pB + j0);
        float4 pB1 = *(const float4*)(pB + 256 + j0);
        float4 qB0 = *(const float4*)(qB + j0);
        float4 qB1 = *(const float4*)(qB + 256 + j0);

        float sA = 0.0f, sB = 0.0f;
        sA = fmaf(fmaxf(pA0.x + qA0.x, 0.0f), w0.x, sA);
        sA = fmaf(fmaxf(pA0.y + qA0.y, 0.0f), w0.y, sA);
        sA = fmaf(fmaxf(pA0.z + qA0.z, 0.0f), w0.z, sA);
        sA = fmaf(fmaxf(pA0.w + qA0.w, 0.0f), w0.w, sA);
        sA = fmaf(fmaxf(pA1.x + qA1.x, 0.0f), w1.x, sA);
        sA = fmaf(fmaxf(pA1.y + qA1.y, 0.0f), w1.y, sA);
        sA = fmaf(fmaxf(pA1.z + qA1.z, 0.0f), w1.z, sA);
        sA = fmaf(fmaxf(pA1.w + qA1.w, 0.0f), w1.w, sA);
        sB = fmaf(fmaxf(pB0.x + qB0.x, 0.0f), w0.x, sB);
        sB = fmaf(fmaxf(pB0.y + qB0.y, 0.0f), w0.y, sB);
        sB = fmaf(fmaxf(pB0.z + qB0.z, 0.0f), w0.z, sB);
        sB = fmaf(fmaxf(pB0.w + qB0.w, 0.0f), w0.w, sB);
        sB = fmaf(fmaxf(pB1.x + qB1.x, 0.0f), w1.x, sB);
        sB = fmaf(fmaxf(pB1.y + qB1.y, 0.0f), w1.y, sB);
        sB = fmaf(fmaxf(pB1.z + qB1.z, 0.0f), w1.z, sB);
        sB = fmaf(fmaxf(pB1.w + qB1.w, 0.0f), w1.w, sB);

#pragma unroll
        for (int off = 32; off > 0; off >>= 1) {
            sA += __shfl_down(sA, off, 64);
            sB += __shfl_down(sB, off, 64);
        }

        if (lane == 0) {
            float scA = sA + bias2;
            scores[perm[iA]] = scA;
            int liA = iA - e0;
            if (liA < SC_CAP) sc_lds[liA] = scA;
            if (hasB) {
                float scB = sB + bias2;
                scores[perm[iB]] = scB;
                int liB = iB - e0;
                if (liB < SC_CAP) sc_lds[liB] = scB;
            }
        }
    }
    __syncthreads();

    // ---- phase 2: wave per row ----
    const int hv = hierarchy[0];
    for (int r = r0 + w; r < r1; r += 4) {
        const int es = offs[r], ee = offs[r + 1];
        const int d = ee - es;
        if (d == 0) continue;

        float m = -INFINITY;
        for (int j = lane; j < d; j += 64) {
            int li = es - e0 + j;
            float s = (li < SC_CAP) ? sc_lds[li] : scores[perm[es + j]];
            m = fmaxf(m, s);
        }
#pragma unroll
        for (int off = 32; off > 0; off >>= 1)
            m = fmaxf(m, __shfl_down(m, off, 64));
        m = __shfl(m, 0, 64);

        float ssum = 0.0f;
        for (int j = lane; j < d; j += 64) {
            int li = es - e0 + j;
            float s = (li < SC_CAP) ? sc_lds[li] : scores[perm[es + j]];
            ssum += expf(s - m);
        }
#pragma unroll
        for (int off = 32; off > 0; off >>= 1)
            ssum += __shfl_down(ssum, off, 64);
        ssum = __shfl(ssum, 0, 64);

        for (int j = lane; j < d; j += 64) {
            int li = es - e0 + j;
            float s = (li < SC_CAP) ? sc_lds[li] : scores[perm[es + j]];
            float p = expf(s - m) / ssum;
            float logits = logf(p) - log1pf(-p);   // +inf when p==1 (d==1)
            int oe = perm[es + j];
            float uu = u[oe];
            float L = logf(uu) - log1pf(-uu);
            float y = 1.0f / (1.0f + expf(-(logits + L)));
            bool hard = y > 0.5f;                  // ST forward value == y_hard
            int mm = hard ? (hv + 1) : edge_mask[oe];
            out_y[oe]      = hard ? 1.0f : 0.0f;
            out_mask[oe]   = (float)mm;
            out_causal[oe] = (mm > 0)   ?  s : 0.0f;
            out_spu[oe]    = (mm == -1) ? -s : 0.0f;
        }
    }
}

// ---------------------------------------------------------------------------
extern "C" void kernel_launch(void* const* d_in, const int* in_sizes, int n_in,
                              void* d_out, int out_size, void* d_ws, size_t ws_size,
                              hipStream_t stream) {
    const float* h_ptr = (const float*)d_in[0];
    const float* W1    = (const float*)d_in[1];
    const float* b1    = (const float*)d_in[2];
    const float* W2    = (const float*)d_in[3];
    const float* b2    = (const float*)d_in[4];
    const float* u     = (const float*)d_in[5];
    const int*   row   = (const int*)d_in[6];
    const int*   col   = (const int*)d_in[7];
    const int*   emask = (const int*)d_in[8];
    const int*   hier  = (const int*)d_in[9];

    float* out        = (float*)d_out;
    float* scores     = out;                        // [E]
    float* out_y      = out + (size_t)N_EDGES;      // [E]
    float* out_mask   = out + 2 * (size_t)N_EDGES;  // [E]
    float* out_causal = out + 3 * (size_t)N_EDGES;  // [E]
    float* out_spu    = out + 4 * (size_t)N_EDGES;  // [E]

    // workspace (4B units), PQ first for 16B alignment:
    float* PQ     = (float*)d_ws;
    int*   deg    = (int*)(PQ + (size_t)N_NODES * PQ_STRIDE);
    int*   cursor = deg + N_NODES;
    int*   offs   = cursor + N_NODES;               // [N_NODES+1]
    int*   totals = offs + N_NODES + 1;             // [32]
    int*   perm   = totals + 32;
    int*   row_s  = perm + N_EDGES;
    int*   col_s  = row_s + N_EDGES;

    {
        void* args[] = { (void*)&row, (void*)&col, (void*)&deg, (void*)&totals,
                         (void*)&cursor, (void*)&offs, (void*)&perm,
                         (void*)&row_s, (void*)&col_s };
        hipLaunchCooperativeKernel((const void*)build_csr, dim3(CSR_BLOCKS),
                                   dim3(1024), args, 0, stream);
    }

    dim3 ggrid(PQ_STRIDE / TN, (N_NODES + TM - 1) / TM);  // 8 x 157
    hipLaunchKernelGGL(gemm_pq, ggrid, dim3(512), 0, stream, h_ptr, W1, b1, PQ);

    hipLaunchKernelGGL(fused_edge, dim3((N_NODES + ROWS_PER_BLOCK - 1) / ROWS_PER_BLOCK),
                       dim3(256), 0, stream,
                       PQ, W2, b2, row_s, col_s, perm, offs, u, emask, hier,
                       scores, out_y, out_mask, out_causal, out_spu);
}

// Round 7
// 388.987 us; speedup vs baseline: 1.0391x; 1.0391x over previous
//
#include <hip/hip_runtime.h>
#include <math.h>

#define N_NODES 20000
#define N_EDGES 320000
#define EMB 128
#define HID 512          // 4*EMB
#define PQ_STRIDE 1024   // P (512, bias-folded) + Q (512) per node
#define ROWS_PER_BLOCK 16
#define SC_CAP 2048      // LDS score cache per block

typedef float v2f __attribute__((ext_vector_type(2)));

#if defined(__has_builtin)
#if __has_builtin(__builtin_elementwise_fma)
#define V2FMA(a, b, c) __builtin_elementwise_fma((a), (b), (c))
#else
#define V2FMA(a, b, c) ((a) * (b) + (c))
#endif
#else
#define V2FMA(a, b, c) ((a) * (b) + (c))
#endif

// ---------------------------------------------------------------------------
#define TM 128
#define TN 128
#define BK 16
#define NTILES (EMB / BK)        // 8
#define GEMM_MT ((N_NODES + TM - 1) / TM)   // 157
#define GEMM_BLOCKS (8 * GEMM_MT)           // 1256
#define INIT_BLOCKS 40                       // 40*512 = 20480 >= N_NODES

// ---------------------------------------------------------------------------
// K1: gemm blocks [0,1256) compute PQ; tail blocks zero deg + init sentinel
// and the K2 ticket counter. Independent work — no ordering needed.
// ---------------------------------------------------------------------------
__global__ __launch_bounds__(512) void gemm_init(
    const float* __restrict__ h, const float* __restrict__ W1,
    const float* __restrict__ b1, float* __restrict__ PQ,
    int* __restrict__ deg, int* __restrict__ offs, int* __restrict__ ticket)
{
    const int bid = blockIdx.x;
    const int tid = threadIdx.x;

    if (bid >= GEMM_BLOCKS) {
        // ---- init path ----
        const int idx = (bid - GEMM_BLOCKS) * 512 + tid;
        if (idx < N_NODES) deg[idx] = 0;
        if (idx == 0) { offs[N_NODES] = N_EDGES; *ticket = 0; }
        return;
    }

    // ---- gemm path: 128x128 tile, 8 waves, LDS double-buffer ----
    __shared__ float As[2][BK][TM + 4];
    __shared__ float Bs[2][BK][TN];

    const int nt = bid & 7;            // 0..7 (col tile of 128 over 1024)
    const int mt = bid >> 3;           // 0..156
    const int m_base = mt * TM;

    const int a_m = tid >> 2;          // 0..127
    const int a_k = (tid & 3) << 2;    // 0,4,8,12
    const int  row_a = m_base + a_m;
    const bool a_ok  = row_a < N_NODES;
    const float* __restrict__ hrow = h + (size_t)row_a * EMB + a_k;

    const int b_k = tid >> 5;          // 0..15
    const int b_n = (tid & 31) << 2;   // 0..124
    const int w_row_off = (nt < 4) ? 0 : 128;
    const int w_col     = (nt & 3) * TN + b_n;
    const float* __restrict__ wrow = W1 + (size_t)(w_row_off + b_k) * HID + w_col;

    const int ty = tid >> 4, tx = tid & 15;
    const int cm = ty << 2, cn = tx << 2;

    v2f acc[4][4] = {};

    float4 pa, pb;
    pa = make_float4(0.f, 0.f, 0.f, 0.f);
    if (a_ok) pa = *(const float4*)(hrow);
    pb = *(const float4*)(wrow);
    As[0][a_k + 0][a_m] = pa.x;
    As[0][a_k + 1][a_m] = pa.y;
    As[0][a_k + 2][a_m] = pa.z;
    As[0][a_k + 3][a_m] = pa.w;
    *(float4*)&Bs[0][b_k][b_n] = pb;
    __syncthreads();

    for (int t = 0; t < NTILES; ++t) {
        const int cur = t & 1;
        if (t + 1 < NTILES) {
            const int k0 = (t + 1) * BK;
            pa = make_float4(0.f, 0.f, 0.f, 0.f);
            if (a_ok) pa = *(const float4*)(hrow + k0);
            pb = *(const float4*)(wrow + (size_t)k0 * HID);
        }

#pragma unroll
        for (int kk = 0; kk < BK; ++kk) {
            float4 a4 = *(const float4*)&As[cur][kk][cm];
            float4 b0 = *(const float4*)&Bs[cur][kk][cn];
            float4 b1v = *(const float4*)&Bs[cur][kk][cn + 64];
            v2f bp[4] = {(v2f){b0.x, b0.y}, (v2f){b0.z, b0.w},
                         (v2f){b1v.x, b1v.y}, (v2f){b1v.z, b1v.w}};
            float a[4] = {a4.x, a4.y, a4.z, a4.w};
#pragma unroll
            for (int i = 0; i < 4; ++i) {
                v2f ai = (v2f){a[i], a[i]};
#pragma unroll
                for (int j = 0; j < 4; ++j)
                    acc[i][j] = V2FMA(ai, bp[j], acc[i][j]);
            }
        }

        if (t + 1 < NTILES) {
            const int nxt = 1 - cur;
            As[nxt][a_k + 0][a_m] = pa.x;
            As[nxt][a_k + 1][a_m] = pa.y;
            As[nxt][a_k + 2][a_m] = pa.z;
            As[nxt][a_k + 3][a_m] = pa.w;
            *(float4*)&Bs[nxt][b_k][b_n] = pb;
            __syncthreads();
        }
    }

    const int col_base = nt * TN;
    v2f bias[4] = {{0.f,0.f},{0.f,0.f},{0.f,0.f},{0.f,0.f}};
    if (nt < 4) {  // bias fold: P half only
        float4 bv0 = *(const float4*)(b1 + col_base + cn);
        float4 bv1 = *(const float4*)(b1 + col_base + cn + 64);
        bias[0] = (v2f){bv0.x, bv0.y};
        bias[1] = (v2f){bv0.z, bv0.w};
        bias[2] = (v2f){bv1.x, bv1.y};
        bias[3] = (v2f){bv1.z, bv1.w};
    }

#pragma unroll
    for (int i = 0; i < 4; ++i) {
        const int r = m_base + cm + i;
        if (r < N_NODES) {
            float* dst = PQ + (size_t)r * PQ_STRIDE + col_base;
            v2f c0 = acc[i][0] + bias[0], c1 = acc[i][1] + bias[1];
            v2f c2 = acc[i][2] + bias[2], c3 = acc[i][3] + bias[3];
            *(float4*)(dst + cn)      = make_float4(c0.x, c0.y, c1.x, c1.y);
            *(float4*)(dst + cn + 64) = make_float4(c2.x, c2.y, c3.x, c3.y);
        }
    }
}

// ---------------------------------------------------------------------------
__device__ __forceinline__ int wave_incl_scan(int v, int lane) {
#pragma unroll
    for (int off = 1; off < 64; off <<= 1) {
        int t = __shfl_up(v, off, 64);
        if (lane >= off) v += t;
    }
    return v;
}

// ---------------------------------------------------------------------------
// K2: degree histogram; the LAST block to finish (device ticket) runs the
// exclusive scan in-block (20 chunk iterations over 1024 threads).
// deg reads in the scan use agent-scope atomic loads (L1 bypass).
// ---------------------------------------------------------------------------
#define HIST_BLOCKS ((N_EDGES + 1023) / 1024)   // 313

__global__ __launch_bounds__(1024) void hist_scan(
    const int* __restrict__ row, int* __restrict__ deg,
    int* __restrict__ ticket, int* __restrict__ cursor, int* __restrict__ offs)
{
    const int tid = threadIdx.x, lane = tid & 63, w = tid >> 6;
    __shared__ int wsum[16];
    __shared__ int chunk_total;
    __shared__ int carry_s;
    __shared__ int is_last;

    const int e = blockIdx.x * 1024 + tid;
    if (e < N_EDGES) atomicAdd(&deg[row[e]], 1);

    __threadfence();
    __syncthreads();
    if (tid == 0) is_last = (atomicAdd(ticket, 1) == gridDim.x - 1) ? 1 : 0;
    __syncthreads();
    if (!is_last) return;

    // ---- last block: exclusive scan over deg -> cursor + offs ----
    if (tid == 0) carry_s = 0;
    __syncthreads();
    for (int base = 0; base < N_NODES; base += 1024) {
        int i = base + tid;
        int v = 0;
        if (i < N_NODES)
            v = __hip_atomic_load(&deg[i], __ATOMIC_RELAXED, __HIP_MEMORY_SCOPE_AGENT);
        int incl = wave_incl_scan(v, lane);
        if (lane == 63) wsum[w] = incl;
        __syncthreads();
        if (w == 0) {
            int x = (lane < 16) ? wsum[lane] : 0;
            int xs = wave_incl_scan(x, lane);
            if (lane == 15) chunk_total = xs;
            if (lane < 16) wsum[lane] = xs - x;   // exclusive wave offsets
        }
        __syncthreads();
        int excl = carry_s + wsum[w] + incl - v;
        if (i < N_NODES) { cursor[i] = excl; offs[i] = excl; }
        __syncthreads();
        if (tid == 0) carry_s += chunk_total;
        __syncthreads();
    }
}

// ---------------------------------------------------------------------------
// K3: scatter edges into row-sorted order
// ---------------------------------------------------------------------------
__global__ void scatter_edges(const int* __restrict__ row, const int* __restrict__ col,
                              int* __restrict__ cursor, int* __restrict__ perm,
                              int* __restrict__ row_s, int* __restrict__ col_s) {
    int e = blockIdx.x * 256 + threadIdx.x;
    if (e >= N_EDGES) return;
    int r = row[e];
    int pos = atomicAdd(&cursor[r], 1);
    perm[pos] = e;
    row_s[pos] = r;
    col_s[pos] = col[e];
}

// ---------------------------------------------------------------------------
// K4: fused edge phase (round-4 champion config: RPB=16, x2 unroll).
// Phase 1: wave-per-edge MLP scores -> LDS + global. Phase 2: wave-per-row
// segment softmax + relaxed bernoulli + straight-through outputs.
// ---------------------------------------------------------------------------
__global__ __launch_bounds__(256) void fused_edge(
    const float* __restrict__ PQ,
    const float* __restrict__ W2, const float* __restrict__ b2,
    const int* __restrict__ row_s, const int* __restrict__ col_s,
    const int* __restrict__ perm, const int* __restrict__ offs,
    const float* __restrict__ u, const int* __restrict__ edge_mask,
    const int* __restrict__ hierarchy,
    float* __restrict__ scores, float* __restrict__ out_y,
    float* __restrict__ out_mask, float* __restrict__ out_causal,
    float* __restrict__ out_spu)
{
    __shared__ float sc_lds[SC_CAP];

    const int r0 = blockIdx.x * ROWS_PER_BLOCK;
    const int r1 = (r0 + ROWS_PER_BLOCK < N_NODES) ? r0 + ROWS_PER_BLOCK : N_NODES;
    const int e0 = offs[r0];
    const int e1 = offs[r1];
    const int tid = threadIdx.x, lane = tid & 63, w = tid >> 6;
    const int j0 = lane << 2;

    const float4 w0 = *(const float4*)(W2 + j0);
    const float4 w1 = *(const float4*)(W2 + 256 + j0);
    const float bias2 = b2[0];

    // ---- phase 1: scores, two edges per wave-iteration ----
    for (int i0 = e0 + (w << 1); i0 < e1; i0 += 8) {
        const int  iA   = i0;
        const bool hasB = (i0 + 1) < e1;
        const int  iB   = hasB ? i0 + 1 : i0;

        const int rA = row_s[iA], cA = col_s[iA];
        const int rB = row_s[iB], cB = col_s[iB];
        const float* __restrict__ pA = PQ + (size_t)rA * PQ_STRIDE;
        const float* __restrict__ qA = PQ + (size_t)cA * PQ_STRIDE + HID;
        const float* __restrict__ pB = PQ + (size_t)rB * PQ_STRIDE;
        const float* __restrict__ qB = PQ + (size_t)cB * PQ_STRIDE + HID;

        float4 pA0 = *(const float4*)(pA + j0);
        float4 pA1 = *(const float4*)(pA + 256 + j0);
        float4 qA0 = *(const float4*)(qA + j0);
        float4 qA1 = *(const float4*)(qA + 256 + j0);
        float4 pB0 = *(const float4*)(pB + j0);
        float4 pB1 = *(const float4*)(pB + 256 + j0);
        float4 qB0 = *(const float4*)(qB + j0);
        float4 qB1 = *(const float4*)(qB + 256 + j0);

        float sA = 0.0f, sB = 0.0f;
        sA = fmaf(fmaxf(pA0.x + qA0.x, 0.0f), w0.x, sA);
        sA = fmaf(fmaxf(pA0.y + qA0.y, 0.0f), w0.y, sA);
        sA = fmaf(fmaxf(pA0.z + qA0.z, 0.0f), w0.z, sA);
        sA = fmaf(fmaxf(pA0.w + qA0.w, 0.0f), w0.w, sA);
        sA = fmaf(fmaxf(pA1.x + qA1.x, 0.0f), w1.x, sA);
        sA = fmaf(fmaxf(pA1.y + qA1.y, 0.0f), w1.y, sA);
        sA = fmaf(fmaxf(pA1.z + qA1.z, 0.0f), w1.z, sA);
        sA = fmaf(fmaxf(pA1.w + qA1.w, 0.0f), w1.w, sA);
        sB = fmaf(fmaxf(pB0.x + qB0.x, 0.0f), w0.x, sB);
        sB = fmaf(fmaxf(pB0.y + qB0.y, 0.0f), w0.y, sB);
        sB = fmaf(fmaxf(pB0.z + qB0.z, 0.0f), w0.z, sB);
        sB = fmaf(fmaxf(pB0.w + qB0.w, 0.0f), w0.w, sB);
        sB = fmaf(fmaxf(pB1.x + qB1.x, 0.0f), w1.x, sB);
        sB = fmaf(fmaxf(pB1.y + qB1.y, 0.0f), w1.y, sB);
        sB = fmaf(fmaxf(pB1.z + qB1.z, 0.0f), w1.z, sB);
        sB = fmaf(fmaxf(pB1.w + qB1.w, 0.0f), w1.w, sB);

#pragma unroll
        for (int off = 32; off > 0; off >>= 1) {
            sA += __shfl_down(sA, off, 64);
            sB += __shfl_down(sB, off, 64);
        }

        if (lane == 0) {
            float scA = sA + bias2;
            scores[perm[iA]] = scA;
            int liA = iA - e0;
            if (liA < SC_CAP) sc_lds[liA] = scA;
            if (hasB) {
                float scB = sB + bias2;
                scores[perm[iB]] = scB;
                int liB = iB - e0;
                if (liB < SC_CAP) sc_lds[liB] = scB;
            }
        }
    }
    __syncthreads();

    // ---- phase 2: wave per row ----
    const int hv = hierarchy[0];
    for (int r = r0 + w; r < r1; r += 4) {
        const int es = offs[r], ee = offs[r + 1];
        const int d = ee - es;
        if (d == 0) continue;

        float m = -INFINITY;
        for (int j = lane; j < d; j += 64) {
            int li = es - e0 + j;
            float s = (li < SC_CAP) ? sc_lds[li] : scores[perm[es + j]];
            m = fmaxf(m, s);
        }
#pragma unroll
        for (int off = 32; off > 0; off >>= 1)
            m = fmaxf(m, __shfl_down(m, off, 64));
        m = __shfl(m, 0, 64);

        float ssum = 0.0f;
        for (int j = lane; j < d; j += 64) {
            int li = es - e0 + j;
            float s = (li < SC_CAP) ? sc_lds[li] : scores[perm[es + j]];
            ssum += expf(s - m);
        }
#pragma unroll
        for (int off = 32; off > 0; off >>= 1)
            ssum += __shfl_down(ssum, off, 64);
        ssum = __shfl(ssum, 0, 64);

        for (int j = lane; j < d; j += 64) {
            int li = es - e0 + j;
            float s = (li < SC_CAP) ? sc_lds[li] : scores[perm[es + j]];
            float p = expf(s - m) / ssum;
            float logits = logf(p) - log1pf(-p);   // +inf when p==1 (d==1)
            int oe = perm[es + j];
            float uu = u[oe];
            float L = logf(uu) - log1pf(-uu);
            float y = 1.0f / (1.0f + expf(-(logits + L)));
            bool hard = y > 0.5f;                  // ST forward value == y_hard
            int mm = hard ? (hv + 1) : edge_mask[oe];
            out_y[oe]      = hard ? 1.0f : 0.0f;
            out_mask[oe]   = (float)mm;
            out_causal[oe] = (mm > 0)   ?  s : 0.0f;
            out_spu[oe]    = (mm == -1) ? -s : 0.0f;
        }
    }
}

// ---------------------------------------------------------------------------
extern "C" void kernel_launch(void* const* d_in, const int* in_sizes, int n_in,
                              void* d_out, int out_size, void* d_ws, size_t ws_size,
                              hipStream_t stream) {
    const float* h_ptr = (const float*)d_in[0];
    const float* W1    = (const float*)d_in[1];
    const float* b1    = (const float*)d_in[2];
    const float* W2    = (const float*)d_in[3];
    const float* b2    = (const float*)d_in[4];
    const float* u     = (const float*)d_in[5];
    const int*   row   = (const int*)d_in[6];
    const int*   col   = (const int*)d_in[7];
    const int*   emask = (const int*)d_in[8];
    const int*   hier  = (const int*)d_in[9];

    float* out        = (float*)d_out;
    float* scores     = out;                        // [E]
    float* out_y      = out + (size_t)N_EDGES;      // [E]
    float* out_mask   = out + 2 * (size_t)N_EDGES;  // [E]
    float* out_causal = out + 3 * (size_t)N_EDGES;  // [E]
    float* out_spu    = out + 4 * (size_t)N_EDGES;  // [E]

    // workspace (4B units), PQ first for 16B alignment:
    float* PQ     = (float*)d_ws;
    int*   deg    = (int*)(PQ + (size_t)N_NODES * PQ_STRIDE);
    int*   cursor = deg + N_NODES;
    int*   offs   = cursor + N_NODES;               // [N_NODES+1]
    int*   ticket = offs + N_NODES + 1;             // [1]
    int*   perm   = ticket + 1;
    int*   row_s  = perm + N_EDGES;
    int*   col_s  = row_s + N_EDGES;

    // K1: gemm + init (heterogeneous blocks, independent work)
    hipLaunchKernelGGL(gemm_init, dim3(GEMM_BLOCKS + INIT_BLOCKS), dim3(512), 0, stream,
                       h_ptr, W1, b1, PQ, deg, offs, ticket);

    // K2: histogram + last-block scan
    hipLaunchKernelGGL(hist_scan, dim3(HIST_BLOCKS), dim3(1024), 0, stream,
                       row, deg, ticket, cursor, offs);

    // K3: scatter into row-sorted order
    hipLaunchKernelGGL(scatter_edges, dim3((N_EDGES + 255) / 256), dim3(256), 0, stream,
                       row, col, cursor, perm, row_s, col_s);

    // K4: fused scores + softmax + bernoulli + outputs
    hipLaunchKernelGGL(fused_edge, dim3((N_NODES + ROWS_PER_BLOCK - 1) / ROWS_PER_BLOCK),
                       dim3(256), 0, stream,
                       PQ, W2, b2, row_s, col_s, perm, offs, u, emask, hier,
                       scores, out_y, out_mask, out_causal, out_spu);
}

// Round 8
// 302.826 us; speedup vs baseline: 1.3348x; 1.2845x over previous
//
#include <hip/hip_runtime.h>
#include <math.h>

#define N_NODES 20000
#define N_EDGES 320000
#define EMB 128
#define HID 512          // 4*EMB
#define PQ_STRIDE 1024   // P (512, bias-folded) + Q (512) per node
#define ROWS_PER_BLOCK 16
#define SC_CAP 2048      // LDS score cache per block
#define NCHUNK ((N_NODES + 1023) / 1024)   // 20

typedef float v2f __attribute__((ext_vector_type(2)));

#if defined(__has_builtin)
#if __has_builtin(__builtin_elementwise_fma)
#define V2FMA(a, b, c) __builtin_elementwise_fma((a), (b), (c))
#else
#define V2FMA(a, b, c) ((a) * (b) + (c))
#endif
#else
#define V2FMA(a, b, c) ((a) * (b) + (c))
#endif

// ---------------------------------------------------------------------------
__global__ void init_deg(int* __restrict__ deg, int* __restrict__ offs) {
    int i = blockIdx.x * 256 + threadIdx.x;
    if (i < N_NODES) deg[i] = 0;
    if (i == 0) offs[N_NODES] = N_EDGES;
}

__global__ void histogram_rows(const int* __restrict__ row, int* __restrict__ deg) {
    int e = blockIdx.x * 256 + threadIdx.x;
    if (e < N_EDGES) atomicAdd(&deg[row[e]], 1);
}

// ---------------------------------------------------------------------------
// hierarchical exclusive scan (3 tiny kernels — measured faster than both the
// single-block serial scan and the coop/ticket variants)
// ---------------------------------------------------------------------------
__device__ __forceinline__ int wave_incl_scan(int v, int lane) {
#pragma unroll
    for (int off = 1; off < 64; off <<= 1) {
        int t = __shfl_up(v, off, 64);
        if (lane >= off) v += t;
    }
    return v;
}

__global__ __launch_bounds__(1024) void scan_part(const int* __restrict__ deg,
                                                  int* __restrict__ part,
                                                  int* __restrict__ totals) {
    __shared__ int wsum[16];
    const int tid = threadIdx.x, lane = tid & 63, w = tid >> 6;
    const int i = blockIdx.x * 1024 + tid;
    int v = (i < N_NODES) ? deg[i] : 0;
    int incl = wave_incl_scan(v, lane);
    if (lane == 63) wsum[w] = incl;
    __syncthreads();
    if (w == 0) {
        int x = (lane < 16) ? wsum[lane] : 0;
        int xs = wave_incl_scan(x, lane);
        if (lane < 16) wsum[lane] = xs - x;
        if (lane == 15) totals[blockIdx.x] = xs;
    }
    __syncthreads();
    if (i < N_NODES) part[i] = wsum[w] + incl - v;
}

__global__ void scan_carry(const int* __restrict__ totals, int* __restrict__ carry) {
    const int lane = threadIdx.x;   // one wave
    int v = (lane < NCHUNK) ? totals[lane] : 0;
    int incl = wave_incl_scan(v, lane);
    if (lane < NCHUNK) carry[lane] = incl - v;
}

__global__ __launch_bounds__(1024) void scan_apply(const int* __restrict__ part,
                                                   const int* __restrict__ carry,
                                                   int* __restrict__ cursor,
                                                   int* __restrict__ offs) {
    const int i = blockIdx.x * 1024 + threadIdx.x;
    if (i < N_NODES) {
        int o = part[i] + carry[blockIdx.x];
        cursor[i] = o;
        offs[i] = o;
    }
}

// ---------------------------------------------------------------------------
// scatter: ONE int2 {e, row<<16|col} per edge (replaces 3 separate stores;
// row,col < 32768 so the pack is lossless). perm array eliminated.
// ---------------------------------------------------------------------------
__global__ void scatter_edges(const int* __restrict__ row, const int* __restrict__ col,
                              int* __restrict__ cursor, int2* __restrict__ rc2) {
    int e = blockIdx.x * 256 + threadIdx.x;
    if (e >= N_EDGES) return;
    int r = row[e];
    int pos = atomicAdd(&cursor[r], 1);
    rc2[pos] = make_int2(e, (r << 16) | col[e]);
}

// ---------------------------------------------------------------------------
// GEMM: PQ[:,0:512] = h@W1[0:128,:] + b1 ; PQ[:,512:1024] = h@W1[128:256,:]
// 128x128 tile, BK=8, 256 threads (4 waves), 8x8 micro-tile (pk-fma),
// LDS double-buffer (16.6 KB -> 8 blocks/CU). Per kk: 4 ds_read_b128 (48cyc)
// per 32 v_pk_fma (64cyc) — FMA-bound, vs the old 4x8 tile's 36:32 LDS-bound.
// ---------------------------------------------------------------------------
#define TM 128
#define TN 128
#define BK 8
#define NTILES (EMB / BK)   // 16

__global__ __launch_bounds__(256) void gemm_pq(
    const float* __restrict__ h, const float* __restrict__ W1,
    const float* __restrict__ b1, float* __restrict__ PQ)
{
    __shared__ float As[2][BK][TM + 4];   // transposed A, stride 132
    __shared__ float Bs[2][BK][TN];

    const int tid = threadIdx.x;
    const int nt  = blockIdx.x;           // 0..7
    const int mt  = blockIdx.y;           // 0..156
    const int m_base = mt * TM;

    // A staging: 128 rows x 8 k = 256 float4 -> 1 per thread
    const int a_m = tid >> 1;             // 0..127
    const int a_k = (tid & 1) << 2;       // 0 or 4
    const int  row_a = m_base + a_m;
    const bool a_ok  = row_a < N_NODES;
    const float* __restrict__ hrow = h + (size_t)row_a * EMB + a_k;

    // B staging: 8 rows x 128 cols = 256 float4 -> 1 per thread
    const int b_k = tid >> 5;             // 0..7
    const int b_n = (tid & 31) << 2;      // 0..124
    const int w_row_off = (nt < 4) ? 0 : 128;
    const int w_col     = (nt & 3) * TN + b_n;
    const float* __restrict__ wrow = W1 + (size_t)(w_row_off + b_k) * HID + w_col;

    // compute: 16x16 threads, rows {cm..cm+3, cm+64..cm+67}, cols likewise
    const int ty = tid >> 4, tx = tid & 15;
    const int cm = ty << 2, cn = tx << 2;

    v2f acc[8][4] = {};   // [i<4: row cm+i | i>=4: cm+64+i-4]
                          // [pair j: (cn,cn+1)(cn+2,cn+3)(cn+64,65)(cn+66,67)]

    float4 pa, pb;
    pa = make_float4(0.f, 0.f, 0.f, 0.f);
    if (a_ok) pa = *(const float4*)(hrow);
    pb = *(const float4*)(wrow);
    As[0][a_k + 0][a_m] = pa.x;
    As[0][a_k + 1][a_m] = pa.y;
    As[0][a_k + 2][a_m] = pa.z;
    As[0][a_k + 3][a_m] = pa.w;
    *(float4*)&Bs[0][b_k][b_n] = pb;
    __syncthreads();

    for (int t = 0; t < NTILES; ++t) {
        const int cur = t & 1;
        if (t + 1 < NTILES) {
            const int k0 = (t + 1) * BK;
            pa = make_float4(0.f, 0.f, 0.f, 0.f);
            if (a_ok) pa = *(const float4*)(hrow + k0);
            pb = *(const float4*)(wrow + (size_t)k0 * HID);
        }

#pragma unroll
        for (int kk = 0; kk < BK; ++kk) {
            float a[8];
            *(float4*)&a[0] = *(const float4*)&As[cur][kk][cm];
            *(float4*)&a[4] = *(const float4*)&As[cur][kk][cm + 64];
            float4 b0 = *(const float4*)&Bs[cur][kk][cn];
            float4 b1v = *(const float4*)&Bs[cur][kk][cn + 64];
            v2f bp[4] = {(v2f){b0.x, b0.y}, (v2f){b0.z, b0.w},
                         (v2f){b1v.x, b1v.y}, (v2f){b1v.z, b1v.w}};
#pragma unroll
            for (int i = 0; i < 8; ++i) {
                v2f ai = (v2f){a[i], a[i]};
#pragma unroll
                for (int j = 0; j < 4; ++j)
                    acc[i][j] = V2FMA(ai, bp[j], acc[i][j]);
            }
        }

        if (t + 1 < NTILES) {
            const int nxt = 1 - cur;
            As[nxt][a_k + 0][a_m] = pa.x;
            As[nxt][a_k + 1][a_m] = pa.y;
            As[nxt][a_k + 2][a_m] = pa.z;
            As[nxt][a_k + 3][a_m] = pa.w;
            *(float4*)&Bs[nxt][b_k][b_n] = pb;
            __syncthreads();
        }
    }

    const int col_base = nt * TN;
    v2f bias[4] = {{0.f,0.f},{0.f,0.f},{0.f,0.f},{0.f,0.f}};
    if (nt < 4) {  // bias fold: P half only
        float4 bv0 = *(const float4*)(b1 + col_base + cn);
        float4 bv1 = *(const float4*)(b1 + col_base + cn + 64);
        bias[0] = (v2f){bv0.x, bv0.y};
        bias[1] = (v2f){bv0.z, bv0.w};
        bias[2] = (v2f){bv1.x, bv1.y};
        bias[3] = (v2f){bv1.z, bv1.w};
    }

#pragma unroll
    for (int i = 0; i < 8; ++i) {
        const int r = m_base + cm + (i < 4 ? i : 64 + i - 4);
        if (r < N_NODES) {
            float* dst = PQ + (size_t)r * PQ_STRIDE + col_base;
            v2f c0 = acc[i][0] + bias[0], c1 = acc[i][1] + bias[1];
            v2f c2 = acc[i][2] + bias[2], c3 = acc[i][3] + bias[3];
            *(float4*)(dst + cn)      = make_float4(c0.x, c0.y, c1.x, c1.y);
            *(float4*)(dst + cn + 64) = make_float4(c2.x, c2.y, c3.x, c3.y);
        }
    }
}

// ---------------------------------------------------------------------------
// Fused edge phase (champion config: RPB=16, x2 unroll). rc2 packs
// {orig_edge, row<<16|col} per sorted slot.
// ---------------------------------------------------------------------------
__global__ __launch_bounds__(256) void fused_edge(
    const float* __restrict__ PQ,
    const float* __restrict__ W2, const float* __restrict__ b2,
    const int2* __restrict__ rc2, const int* __restrict__ offs,
    const float* __restrict__ u, const int* __restrict__ edge_mask,
    const int* __restrict__ hierarchy,
    float* __restrict__ scores, float* __restrict__ out_y,
    float* __restrict__ out_mask, float* __restrict__ out_causal,
    float* __restrict__ out_spu)
{
    __shared__ float sc_lds[SC_CAP];

    const int r0 = blockIdx.x * ROWS_PER_BLOCK;
    const int r1 = (r0 + ROWS_PER_BLOCK < N_NODES) ? r0 + ROWS_PER_BLOCK : N_NODES;
    const int e0 = offs[r0];
    const int e1 = offs[r1];
    const int tid = threadIdx.x, lane = tid & 63, w = tid >> 6;
    const int j0 = lane << 2;

    const float4 w0 = *(const float4*)(W2 + j0);
    const float4 w1 = *(const float4*)(W2 + 256 + j0);
    const float bias2 = b2[0];

    // ---- phase 1: scores, two edges per wave-iteration ----
    for (int i0 = e0 + (w << 1); i0 < e1; i0 += 8) {
        const int  iA   = i0;
        const bool hasB = (i0 + 1) < e1;
        const int  iB   = hasB ? i0 + 1 : i0;

        const int2 eA = rc2[iA];
        const int2 eB = rc2[iB];
        const int rA = ((unsigned)eA.y) >> 16, cA = eA.y & 0xFFFF;
        const int rB = ((unsigned)eB.y) >> 16, cB = eB.y & 0xFFFF;
        const float* __restrict__ pA = PQ + (size_t)rA * PQ_STRIDE;
        const float* __restrict__ qA = PQ + (size_t)cA * PQ_STRIDE + HID;
        const float* __restrict__ pB = PQ + (size_t)rB * PQ_STRIDE;
        const float* __restrict__ qB = PQ + (size_t)cB * PQ_STRIDE + HID;

        float4 pA0 = *(const float4*)(pA + j0);
        float4 pA1 = *(const float4*)(pA + 256 + j0);
        float4 qA0 = *(const float4*)(qA + j0);
        float4 qA1 = *(const float4*)(qA + 256 + j0);
        float4 pB0 = *(const float4*)(pB + j0);
        float4 pB1 = *(const float4*)(pB + 256 + j0);
        float4 qB0 = *(const float4*)(qB + j0);
        float4 qB1 = *(const float4*)(qB + 256 + j0);

        float sA = 0.0f, sB = 0.0f;
        sA = fmaf(fmaxf(pA0.x + qA0.x, 0.0f), w0.x, sA);
        sA = fmaf(fmaxf(pA0.y + qA0.y, 0.0f), w0.y, sA);
        sA = fmaf(fmaxf(pA0.z + qA0.z, 0.0f), w0.z, sA);
        sA = fmaf(fmaxf(pA0.w + qA0.w, 0.0f), w0.w, sA);
        sA = fmaf(fmaxf(pA1.x + qA1.x, 0.0f), w1.x, sA);
        sA = fmaf(fmaxf(pA1.y + qA1.y, 0.0f), w1.y, sA);
        sA = fmaf(fmaxf(pA1.z + qA1.z, 0.0f), w1.z, sA);
        sA = fmaf(fmaxf(pA1.w + qA1.w, 0.0f), w1.w, sA);
        sB = fmaf(fmaxf(pB0.x + qB0.x, 0.0f), w0.x, sB);
        sB = fmaf(fmaxf(pB0.y + qB0.y, 0.0f), w0.y, sB);
        sB = fmaf(fmaxf(pB0.z + qB0.z, 0.0f), w0.z, sB);
        sB = fmaf(fmaxf(pB0.w + qB0.w, 0.0f), w0.w, sB);
        sB = fmaf(fmaxf(pB1.x + qB1.x, 0.0f), w1.x, sB);
        sB = fmaf(fmaxf(pB1.y + qB1.y, 0.0f), w1.y, sB);
        sB = fmaf(fmaxf(pB1.z + qB1.z, 0.0f), w1.z, sB);
        sB = fmaf(fmaxf(pB1.w + qB1.w, 0.0f), w1.w, sB);

#pragma unroll
        for (int off = 32; off > 0; off >>= 1) {
            sA += __shfl_down(sA, off, 64);
            sB += __shfl_down(sB, off, 64);
        }

        if (lane == 0) {
            float scA = sA + bias2;
            scores[eA.x] = scA;
            int liA = iA - e0;
            if (liA < SC_CAP) sc_lds[liA] = scA;
            if (hasB) {
                float scB = sB + bias2;
                scores[eB.x] = scB;
                int liB = iB - e0;
                if (liB < SC_CAP) sc_lds[liB] = scB;
            }
        }
    }
    __syncthreads();

    // ---- phase 2: wave per row ----
    const int hv = hierarchy[0];
    for (int r = r0 + w; r < r1; r += 4) {
        const int es = offs[r], ee = offs[r + 1];
        const int d = ee - es;
        if (d == 0) continue;

        float m = -INFINITY;
        for (int j = lane; j < d; j += 64) {
            int li = es - e0 + j;
            float s = (li < SC_CAP) ? sc_lds[li] : scores[rc2[es + j].x];
            m = fmaxf(m, s);
        }
#pragma unroll
        for (int off = 32; off > 0; off >>= 1)
            m = fmaxf(m, __shfl_down(m, off, 64));
        m = __shfl(m, 0, 64);

        float ssum = 0.0f;
        for (int j = lane; j < d; j += 64) {
            int li = es - e0 + j;
            float s = (li < SC_CAP) ? sc_lds[li] : scores[rc2[es + j].x];
            ssum += expf(s - m);
        }
#pragma unroll
        for (int off = 32; off > 0; off >>= 1)
            ssum += __shfl_down(ssum, off, 64);
        ssum = __shfl(ssum, 0, 64);

        for (int j = lane; j < d; j += 64) {
            int li = es - e0 + j;
            float s = (li < SC_CAP) ? sc_lds[li] : scores[rc2[es + j].x];
            float p = expf(s - m) / ssum;
            float logits = logf(p) - log1pf(-p);   // +inf when p==1 (d==1)
            int oe = rc2[es + j].x;
            float uu = u[oe];
            float L = logf(uu) - log1pf(-uu);
            float y = 1.0f / (1.0f + expf(-(logits + L)));
            bool hard = y > 0.5f;                  // ST forward value == y_hard
            int mm = hard ? (hv + 1) : edge_mask[oe];
            out_y[oe]      = hard ? 1.0f : 0.0f;
            out_mask[oe]   = (float)mm;
            out_causal[oe] = (mm > 0)   ?  s : 0.0f;
            out_spu[oe]    = (mm == -1) ? -s : 0.0f;
        }
    }
}

// ---------------------------------------------------------------------------
extern "C" void kernel_launch(void* const* d_in, const int* in_sizes, int n_in,
                              void* d_out, int out_size, void* d_ws, size_t ws_size,
                              hipStream_t stream) {
    const float* h_ptr = (const float*)d_in[0];
    const float* W1    = (const float*)d_in[1];
    const float* b1    = (const float*)d_in[2];
    const float* W2    = (const float*)d_in[3];
    const float* b2    = (const float*)d_in[4];
    const float* u     = (const float*)d_in[5];
    const int*   row   = (const int*)d_in[6];
    const int*   col   = (const int*)d_in[7];
    const int*   emask = (const int*)d_in[8];
    const int*   hier  = (const int*)d_in[9];

    float* out        = (float*)d_out;
    float* scores     = out;                        // [E]
    float* out_y      = out + (size_t)N_EDGES;      // [E]
    float* out_mask   = out + 2 * (size_t)N_EDGES;  // [E]
    float* out_causal = out + 3 * (size_t)N_EDGES;  // [E]
    float* out_spu    = out + 4 * (size_t)N_EDGES;  // [E]

    // workspace (4B units), PQ first (16B align), rc2 second (8B align):
    float* PQ     = (float*)d_ws;
    int2*  rc2    = (int2*)(PQ + (size_t)N_NODES * PQ_STRIDE);   // [E] int2
    int*   deg    = (int*)(rc2 + N_EDGES);
    int*   cursor = deg + N_NODES;
    int*   offs   = cursor + N_NODES;               // [N_NODES+1]
    int*   part   = offs + N_NODES + 1;
    int*   totals = part + N_NODES;                 // [NCHUNK]
    int*   carry  = totals + NCHUNK;                // [NCHUNK]

    hipLaunchKernelGGL(init_deg, dim3((N_NODES + 255) / 256), dim3(256), 0, stream,
                       deg, offs);
    hipLaunchKernelGGL(histogram_rows, dim3((N_EDGES + 255) / 256), dim3(256), 0, stream,
                       row, deg);
    hipLaunchKernelGGL(scan_part, dim3(NCHUNK), dim3(1024), 0, stream, deg, part, totals);
    hipLaunchKernelGGL(scan_carry, dim3(1), dim3(64), 0, stream, totals, carry);
    hipLaunchKernelGGL(scan_apply, dim3(NCHUNK), dim3(1024), 0, stream,
                       part, carry, cursor, offs);
    hipLaunchKernelGGL(scatter_edges, dim3((N_EDGES + 255) / 256), dim3(256), 0, stream,
                       row, col, cursor, rc2);

    dim3 ggrid(PQ_STRIDE / TN, (N_NODES + TM - 1) / TM);  // 8 x 157
    hipLaunchKernelGGL(gemm_pq, ggrid, dim3(256), 0, stream, h_ptr, W1, b1, PQ);

    hipLaunchKernelGGL(fused_edge, dim3((N_NODES + ROWS_PER_BLOCK - 1) / ROWS_PER_BLOCK),
                       dim3(256), 0, stream,
                       PQ, W2, b2, rc2, offs, u, emask, hier,
                       scores, out_y, out_mask, out_causal, out_spu);
}